// Round 1
// baseline (138.563 us; speedup 1.0000x reference)
//
#include <hip/hip_runtime.h>
#include <hip/hip_bf16.h>

// Problem constants
#define L_DIM 128
#define N_DIM 32
#define C_DIM 128
#define K_DIM 128   // DIM_MLP
#define OUT_DIM 128

typedef __attribute__((ext_vector_type(8))) short short8;
typedef __attribute__((ext_vector_type(4))) float float4v;

static __device__ __forceinline__ short bf16_bits(float f) {
    __bf16 h = (__bf16)f;   // RNE, lowers to v_cvt (packable)
    return __builtin_bit_cast(short, h);
}

// ---------------------------------------------------------------------------
// Kernel 1: precompute
//   blocks 0..511 : P[b,i,k] = x_i·W1a ; Q[b,j,k] = x_j·W1b + b1 ;
//                   V[b,j,c] = relu(x_j·Vw1 + vb1)·Vw2 + vb2      (8 rows/block)
//   blocks 512..575: W2s = attn_w2 swizzled into bf16 MFMA B-fragment order
// ---------------------------------------------------------------------------
__global__ __launch_bounds__(256) void k_pre(
    const float* __restrict__ x,
    const float* __restrict__ attn_w1, const float* __restrict__ attn_b1,
    const float* __restrict__ attn_w2,
    const float* __restrict__ value_w1, const float* __restrict__ value_b1,
    const float* __restrict__ value_w2, const float* __restrict__ value_b2,
    float* __restrict__ P, float* __restrict__ Q, float* __restrict__ V,
    short* __restrict__ W2s)
{
    int bid = blockIdx.x;
    if (bid >= 512) {
        // W2 swizzle: element e = ((((ct*4+mi)*4+quad)*16+col)*8+idx)
        int e = (bid - 512) * 256 + threadIdx.x;      // 64*256 = 16384 elems
        int idx  = e & 7;
        int colr = (e >> 3) & 15;
        int quad = (e >> 7) & 3;
        int mi   = (e >> 9) & 3;
        int ct   = e >> 11;
        int k = quad * 8 + 32 * mi + idx;
        int c = ct * 16 + colr;
        W2s[e] = bf16_bits(attn_w2[k * OUT_DIM + c]);
        return;
    }

    __shared__ float xs[8][C_DIM];
    __shared__ float hvs[8][K_DIM];
    int tid = threadIdx.x;
    int r0  = bid * 8;                                 // first flat row (i*N+b)

    {   // cooperative load of 8 x-rows (1024 floats, 4 per thread)
        int flat = tid * 4;
        int row = flat >> 7, c = flat & 127;
        *(float4v*)(&xs[row][c]) = *(const float4v*)(x + (r0 + row) * C_DIM + c);
    }
    __syncthreads();

    int ks   = tid & 127;      // output column k (or c)
    int half = tid >> 7;       // rows 0-3 vs 4-7

    float pacc[4] = {0,0,0,0}, qacc[4] = {0,0,0,0}, hacc[4] = {0,0,0,0};
    for (int c = 0; c < C_DIM; ++c) {
        float wa = attn_w1[c * K_DIM + ks];
        float wb = attn_w1[(C_DIM + c) * K_DIM + ks];
        float wv = value_w1[c * K_DIM + ks];
        #pragma unroll
        for (int r = 0; r < 4; ++r) {
            float xr = xs[half * 4 + r][c];
            pacc[r] = fmaf(xr, wa, pacc[r]);
            qacc[r] = fmaf(xr, wb, qacc[r]);
            hacc[r] = fmaf(xr, wv, hacc[r]);
        }
    }
    float b1 = attn_b1[ks], vb1 = value_b1[ks];
    #pragma unroll
    for (int r = 0; r < 4; ++r) {
        int rr = r0 + half * 4 + r;
        int i = rr >> 5, b = rr & 31;                  // rr = i*N + b
        P[(b * L_DIM + i) * K_DIM + ks] = pacc[r];
        Q[(b * L_DIM + i) * K_DIM + ks] = qacc[r] + b1;
        hvs[half * 4 + r][ks] = fmaxf(hacc[r] + vb1, 0.f);
    }
    __syncthreads();

    float vacc[4] = {0,0,0,0};
    for (int k = 0; k < K_DIM; ++k) {
        float w = value_w2[k * OUT_DIM + ks];
        #pragma unroll
        for (int r = 0; r < 4; ++r)
            vacc[r] = fmaf(hvs[half * 4 + r][k], w, vacc[r]);
    }
    float vb2 = value_b2[ks];
    #pragma unroll
    for (int r = 0; r < 4; ++r) {
        int rr = r0 + half * 4 + r;
        int i = rr >> 5, b = rr & 31;
        V[(b * L_DIM + i) * OUT_DIM + ks] = vacc[r] + vb2;
    }
}

// ---------------------------------------------------------------------------
// Kernel 2: Sv[b,c] = sum_j V[b,j,c]   (for the b2-bias term)
// ---------------------------------------------------------------------------
__global__ __launch_bounds__(256) void k_sv(const float* __restrict__ V,
                                            float* __restrict__ Sv)
{
    int t = blockIdx.x * 256 + threadIdx.x;  // 4096 = 32*128
    int b = t >> 7, c = t & 127;
    float s = 0.f;
    for (int j = 0; j < L_DIM; ++j)
        s += V[(b * L_DIM + j) * OUT_DIM + c];
    Sv[t] = s;
}

// ---------------------------------------------------------------------------
// Kernel 3: main fused pairwise-MLP + j-reduce.
//   grid = (b=32) x (itile=32); block = 4 waves; wave w handles i = itile*4+w.
//   Per j-tile of 16: A-frag h[j,k] = relu(P[i,k]+Q[j,k]) built in-register,
//   MFMA 16x16x32 bf16 vs W2 B-frags (register-resident), epilogue scales the
//   C-tile rows by V[j,c] and accumulates per-c scalars; xor16/xor32 shuffle
//   finishes the j-sum.
// ---------------------------------------------------------------------------
__global__ __launch_bounds__(256, 2) void k_main(
    const float* __restrict__ P, const float* __restrict__ Q,
    const float* __restrict__ V, const float* __restrict__ Sv,
    const short* __restrict__ W2s, const float* __restrict__ attn_b2,
    float* __restrict__ out)
{
    int b     = blockIdx.x >> 5;
    int itile = blockIdx.x & 31;
    int wave  = threadIdx.x >> 6;
    int lane  = threadIdx.x & 63;
    int i     = itile * 4 + wave;
    int quad  = lane >> 4;
    int col   = lane & 15;

    // B fragments: W2[k = quad*8+32*mi+idx][c = ct*16+col], pre-swizzled
    short8 bfrag[8][4];
    const short8* w2p = (const short8*)W2s;
    #pragma unroll
    for (int ct = 0; ct < 8; ++ct)
        #pragma unroll
        for (int mi = 0; mi < 4; ++mi)
            bfrag[ct][mi] = w2p[((ct * 4 + mi) * 4 + quad) * 16 + col];

    // P fragment (this wave's i-row), same k-pattern as A-frags
    float4v p[4][2];
    const float* Pr = P + (b * L_DIM + i) * K_DIM;
    #pragma unroll
    for (int mi = 0; mi < 4; ++mi) {
        int k0 = quad * 8 + 32 * mi;
        p[mi][0] = *(const float4v*)(Pr + k0);
        p[mi][1] = *(const float4v*)(Pr + k0 + 4);
    }

    float acc[8] = {0,0,0,0,0,0,0,0};

    for (int j0 = 0; j0 < L_DIM; j0 += 16) {
        // A-frags: h[j = j0 + (lane&15)][k = quad*8 + 32*mi + idx]
        const float* Qr = Q + (b * L_DIM + j0 + col) * K_DIM;
        short8 af[4];
        #pragma unroll
        for (int mi = 0; mi < 4; ++mi) {
            int k0 = quad * 8 + 32 * mi;
            float4v q0 = *(const float4v*)(Qr + k0);
            float4v q1 = *(const float4v*)(Qr + k0 + 4);
            short8 a;
            #pragma unroll
            for (int t = 0; t < 4; ++t) {
                a[t]     = bf16_bits(fmaxf(p[mi][0][t] + q0[t], 0.f));
                a[t + 4] = bf16_bits(fmaxf(p[mi][1][t] + q1[t], 0.f));
            }
            af[mi] = a;
        }

        // C/D rows (quad*4+reg) = j within tile -> scale by V[j,c], reduce
        const float* Vr = V + (b * L_DIM + j0 + quad * 4) * OUT_DIM;
        #pragma unroll
        for (int ct = 0; ct < 8; ++ct) {
            float4v c = {0.f, 0.f, 0.f, 0.f};
            #pragma unroll
            for (int mi = 0; mi < 4; ++mi)
                c = __builtin_amdgcn_mfma_f32_16x16x32_bf16(af[mi], bfrag[ct][mi], c, 0, 0, 0);
            int cc = ct * 16 + col;
            #pragma unroll
            for (int r = 0; r < 4; ++r)
                acc[ct] = fmaf(c[r], Vr[r * OUT_DIM + cc], acc[ct]);
        }
    }

    // finish j-sum across quads (lanes sharing the same col)
    #pragma unroll
    for (int ct = 0; ct < 8; ++ct) {
        acc[ct] += __shfl_xor(acc[ct], 16, 64);
        acc[ct] += __shfl_xor(acc[ct], 32, 64);
    }

    if (quad == 0) {
        #pragma unroll
        for (int ct = 0; ct < 8; ++ct) {
            int cc = ct * 16 + col;
            out[(i * N_DIM + b) * OUT_DIM + cc] =
                acc[ct] + attn_b2[cc] * Sv[b * OUT_DIM + cc];
        }
    }
}

// ---------------------------------------------------------------------------
extern "C" void kernel_launch(void* const* d_in, const int* in_sizes, int n_in,
                              void* d_out, int out_size, void* d_ws, size_t ws_size,
                              hipStream_t stream)
{
    const float* x        = (const float*)d_in[0];
    const float* attn_w1  = (const float*)d_in[1];
    const float* attn_b1  = (const float*)d_in[2];
    const float* attn_w2  = (const float*)d_in[3];
    const float* attn_b2  = (const float*)d_in[4];
    const float* value_w1 = (const float*)d_in[5];
    const float* value_b1 = (const float*)d_in[6];
    const float* value_w2 = (const float*)d_in[7];
    const float* value_b2 = (const float*)d_in[8];
    float* out = (float*)d_out;

    // Workspace layout (floats): P 512K | Q 512K | V 512K | Sv 4K | W2s(bf16) 16K
    float* ws  = (float*)d_ws;
    float* P   = ws;
    float* Q   = ws + 524288;
    float* V   = ws + 1048576;
    float* Sv  = ws + 1572864;
    short* W2s = (short*)(ws + 1576960);

    k_pre<<<576, 256, 0, stream>>>(x, attn_w1, attn_b1, attn_w2,
                                   value_w1, value_b1, value_w2, value_b2,
                                   P, Q, V, W2s);
    k_sv<<<16, 256, 0, stream>>>(V, Sv);
    k_main<<<1024, 256, 0, stream>>>(P, Q, V, Sv, W2s, attn_b2, out);
}

// Round 2
// 129.799 us; speedup vs baseline: 1.0675x; 1.0675x over previous
//
#include <hip/hip_runtime.h>
#include <hip/hip_bf16.h>

// Problem constants
#define L_DIM 128
#define N_DIM 32
#define C_DIM 128
#define K_DIM 128   // DIM_MLP
#define OUT_DIM 128

typedef __attribute__((ext_vector_type(8))) short short8;
typedef __attribute__((ext_vector_type(4))) float float4v;
typedef __attribute__((ext_vector_type(2))) float float2v;

static __device__ __forceinline__ short bf16_bits(float f) {
    __bf16 h = (__bf16)f;   // RNE
    return __builtin_bit_cast(short, h);
}

// ---------------------------------------------------------------------------
// Kernel 1: precompute.
//   blocks 0..1023 : 4 flat rows each. P = x·W1a ; Q = x·W1b + b1 ;
//                    V = relu(x·Vw1+vb1)·Vw2 + vb2
//   blocks 1024..1087: W2s = attn_w2 swizzled into bf16 MFMA B-fragment order
// ---------------------------------------------------------------------------
__global__ __launch_bounds__(256) void k_pre(
    const float* __restrict__ x,
    const float* __restrict__ attn_w1, const float* __restrict__ attn_b1,
    const float* __restrict__ attn_w2,
    const float* __restrict__ value_w1, const float* __restrict__ value_b1,
    const float* __restrict__ value_w2, const float* __restrict__ value_b2,
    float* __restrict__ P, float* __restrict__ Q, float* __restrict__ V,
    short* __restrict__ W2s)
{
    int bid = blockIdx.x;
    if (bid >= 1024) {
        // W2 swizzle: element e = ((((ct*4+mi)*4+quad)*16+col)*8+idx)
        int e = (bid - 1024) * 256 + threadIdx.x;     // 64*256 = 16384 elems
        int idx  = e & 7;
        int colr = (e >> 3) & 15;
        int quad = (e >> 7) & 3;
        int mi   = (e >> 9) & 3;
        int ct   = e >> 11;
        int k = quad * 8 + 32 * mi + idx;
        int c = ct * 16 + colr;
        W2s[e] = bf16_bits(attn_w2[k * OUT_DIM + c]);
        return;
    }

    __shared__ float xs[4][C_DIM];
    __shared__ float hvs[4][K_DIM];
    int tid = threadIdx.x;
    int r0  = bid * 4;                                 // first flat row (i*N+b)

    {   // cooperative load of 4 x-rows (512 floats, 2 per thread)
        int f = tid * 2;
        int row = f >> 7, c = f & 127;
        *(float2v*)(&xs[row][c]) = *(const float2v*)(x + (r0 + row) * C_DIM + c);
    }
    __syncthreads();

    int ks   = tid & 127;      // output column k (or c)
    int half = tid >> 7;       // rows 0-1 vs 2-3

    float pacc[2] = {0,0}, qacc[2] = {0,0}, hacc[2] = {0,0};
    #pragma unroll 4
    for (int c = 0; c < C_DIM; ++c) {
        float wa = attn_w1[c * K_DIM + ks];
        float wb = attn_w1[(C_DIM + c) * K_DIM + ks];
        float wv = value_w1[c * K_DIM + ks];
        #pragma unroll
        for (int r = 0; r < 2; ++r) {
            float xr = xs[half * 2 + r][c];
            pacc[r] = fmaf(xr, wa, pacc[r]);
            qacc[r] = fmaf(xr, wb, qacc[r]);
            hacc[r] = fmaf(xr, wv, hacc[r]);
        }
    }
    float b1 = attn_b1[ks], vb1 = value_b1[ks];
    #pragma unroll
    for (int r = 0; r < 2; ++r) {
        int rr = r0 + half * 2 + r;
        int i = rr >> 5, b = rr & 31;                  // rr = i*N + b
        P[(b * L_DIM + i) * K_DIM + ks] = pacc[r];
        Q[(b * L_DIM + i) * K_DIM + ks] = qacc[r] + b1;
        hvs[half * 2 + r][ks] = fmaxf(hacc[r] + vb1, 0.f);
    }
    __syncthreads();

    float vacc[2] = {0,0};
    #pragma unroll 4
    for (int k = 0; k < K_DIM; ++k) {
        float w = value_w2[k * OUT_DIM + ks];
        #pragma unroll
        for (int r = 0; r < 2; ++r)
            vacc[r] = fmaf(hvs[half * 2 + r][k], w, vacc[r]);
    }
    float vb2 = value_b2[ks];
    #pragma unroll
    for (int r = 0; r < 2; ++r) {
        int rr = r0 + half * 2 + r;
        int i = rr >> 5, b = rr & 31;
        V[(b * L_DIM + i) * OUT_DIM + ks] = vacc[r] + vb2;
    }
}

// ---------------------------------------------------------------------------
// Kernel 2: Sv[b,c] = sum_j V[b,j,c]
// ---------------------------------------------------------------------------
__global__ __launch_bounds__(256) void k_sv(const float* __restrict__ V,
                                            float* __restrict__ Sv)
{
    __shared__ float red[256];
    int b = blockIdx.x;                      // 32 blocks
    int tid = threadIdx.x;
    int c = tid & 127, jh = tid >> 7;
    float s = 0.f;
    #pragma unroll 4
    for (int jj = 0; jj < 64; ++jj)
        s += V[(b * L_DIM + jh * 64 + jj) * OUT_DIM + c];
    red[tid] = s;
    __syncthreads();
    if (tid < 128)
        Sv[b * OUT_DIM + tid] = red[tid] + red[128 + tid];
}

// ---------------------------------------------------------------------------
// Kernel 3: fused pairwise-MLP + j-reduce (LDS-pipelined).
//   block = (b, itile); 4 waves; wave w owns i = itile*4 + w, full c range.
//   8 rounds of 16 j's: cooperative Q/V staging (double-buffered) -> bf16
//   A-tile build into XOR-swizzled LDS -> per-wave MFMA vs register-resident
//   W2 fragments -> V-scaled accumulation from LDS.
// ---------------------------------------------------------------------------
#define QV_STRIDE 132   // 128 + 4-float pad

__global__ __launch_bounds__(256)
__attribute__((amdgpu_waves_per_eu(2, 2)))
void k_main(
    const float* __restrict__ P, const float* __restrict__ Q,
    const float* __restrict__ V, const float* __restrict__ Sv,
    const short* __restrict__ W2s, const float* __restrict__ attn_b2,
    float* __restrict__ out)
{
    // LDS: A 16KB | Q/V double-buffered 33KB | P 2KB  => ~51.3 KB
    __shared__ short A_lds[4 * 256 * 8];               // [i][kq][m^kq] x short8
    __shared__ float QV_lds[2][2][16 * QV_STRIDE];     // [buf][q/v][row*132+c]
    __shared__ float P_lds[4 * K_DIM];

    int b     = blockIdx.x >> 5;
    int itile = blockIdx.x & 31;
    int tid   = threadIdx.x;
    int wave  = tid >> 6;
    int lane  = tid & 63;
    int quad  = lane >> 4;
    int col   = lane & 15;
    int i_g   = itile * 4 + wave;

    // B fragments: register-resident W2 (verified swizzle from round 1)
    short8 bfrag[8][4];
    const short8* w2p = (const short8*)W2s;
    #pragma unroll
    for (int ct = 0; ct < 8; ++ct)
        #pragma unroll
        for (int mi = 0; mi < 4; ++mi)
            bfrag[ct][mi] = w2p[((ct * 4 + mi) * 4 + quad) * 16 + col];

    // P tile for this block's 4 i's -> LDS (2 floats/thread)
    {
        int f = tid * 2;
        int ii = f >> 7, k = f & 127;
        *(float2v*)&P_lds[f] =
            *(const float2v*)(P + (b * L_DIM + itile * 4 + ii) * K_DIM + k);
    }

    // staging mapping: row = tid>>4 (16 rows), 8 consecutive floats
    int srow = tid >> 4;
    int sc8  = (tid & 15) * 8;
    const float* Qbase = Q + (size_t)(b * L_DIM) * K_DIM;
    const float* Vbase = V + (size_t)(b * L_DIM) * OUT_DIM;

    // prologue: stage round 0 into buffer 0
    {
        const float* qp = Qbase + (0 * 16 + srow) * K_DIM + sc8;
        const float* vp = Vbase + (0 * 16 + srow) * OUT_DIM + sc8;
        float4v qa = *(const float4v*)qp, qb = *(const float4v*)(qp + 4);
        float4v va = *(const float4v*)vp, vb = *(const float4v*)(vp + 4);
        *(float4v*)&QV_lds[0][0][srow * QV_STRIDE + sc8]     = qa;
        *(float4v*)&QV_lds[0][0][srow * QV_STRIDE + sc8 + 4] = qb;
        *(float4v*)&QV_lds[0][1][srow * QV_STRIDE + sc8]     = va;
        *(float4v*)&QV_lds[0][1][srow * QV_STRIDE + sc8 + 4] = vb;
    }
    __syncthreads();

    float acc[8] = {0,0,0,0,0,0,0,0};
    int cur = 0;

    int m_  = tid >> 4;      // build: row within j-tile (0..15)
    int kq_ = tid & 15;      // build: 8-k group (0..15)

    for (int r = 0; r < 8; ++r) {
        // ---- build A(r): h = relu(P_i + Q_j) in bf16, XOR-swizzled LDS ----
        {
            const float* Qc = &QV_lds[cur][0][m_ * QV_STRIDE + kq_ * 8];
            float4v qa = *(const float4v*)Qc;
            float4v qb = *(const float4v*)(Qc + 4);
            #pragma unroll
            for (int i = 0; i < 4; ++i) {
                float4v pa = *(const float4v*)&P_lds[i * K_DIM + kq_ * 8];
                float4v pb = *(const float4v*)&P_lds[i * K_DIM + kq_ * 8 + 4];
                short8 a;
                #pragma unroll
                for (int t = 0; t < 4; ++t) {
                    a[t]     = bf16_bits(fmaxf(pa[t] + qa[t], 0.f));
                    a[t + 4] = bf16_bits(fmaxf(pb[t] + qb[t], 0.f));
                }
                *(short8*)&A_lds[(i * 256 + kq_ * 16 + (m_ ^ kq_)) * 8] = a;
            }
        }

        // ---- issue next-round global loads (overlap with MFMA) ----
        float4v nqa, nqb, nva, nvb;
        if (r < 7) {
            const float* qp = Qbase + ((r + 1) * 16 + srow) * K_DIM + sc8;
            const float* vp = Vbase + ((r + 1) * 16 + srow) * OUT_DIM + sc8;
            nqa = *(const float4v*)qp; nqb = *(const float4v*)(qp + 4);
            nva = *(const float4v*)vp; nvb = *(const float4v*)(vp + 4);
        }

        __syncthreads();   // A(r) + current QV fully visible

        int nxt = cur ^ 1;
        if (r < 7) {
            *(float4v*)&QV_lds[nxt][0][srow * QV_STRIDE + sc8]     = nqa;
            *(float4v*)&QV_lds[nxt][0][srow * QV_STRIDE + sc8 + 4] = nqb;
            *(float4v*)&QV_lds[nxt][1][srow * QV_STRIDE + sc8]     = nva;
            *(float4v*)&QV_lds[nxt][1][srow * QV_STRIDE + sc8 + 4] = nvb;
        }

        // ---- MFMA phase: this wave's i ----
        short8 af[4];
        #pragma unroll
        for (int ks = 0; ks < 4; ++ks) {
            int kq = ks * 4 + quad;
            af[ks] = *(const short8*)
                &A_lds[(wave * 256 + kq * 16 + (col ^ kq)) * 8];
        }
        const float* Vc = &QV_lds[cur][1][0];
        #pragma unroll
        for (int ct = 0; ct < 8; ++ct) {
            float4v c4 = {0.f, 0.f, 0.f, 0.f};
            #pragma unroll
            for (int ks = 0; ks < 4; ++ks)
                c4 = __builtin_amdgcn_mfma_f32_16x16x32_bf16(
                        af[ks], bfrag[ct][ks], c4, 0, 0, 0);
            int cc = ct * 16 + col;
            #pragma unroll
            for (int rr = 0; rr < 4; ++rr)
                acc[ct] = fmaf(c4[rr], Vc[(quad * 4 + rr) * QV_STRIDE + cc],
                               acc[ct]);
        }

        __syncthreads();   // A(r) consumed; QV[nxt] staged
        cur ^= 1;
    }

    // finish j-sum across quads (lanes sharing the same col)
    #pragma unroll
    for (int ct = 0; ct < 8; ++ct) {
        acc[ct] += __shfl_xor(acc[ct], 16, 64);
        acc[ct] += __shfl_xor(acc[ct], 32, 64);
    }

    if (quad == 0) {
        #pragma unroll
        for (int ct = 0; ct < 8; ++ct) {
            int cc = ct * 16 + col;
            out[(i_g * N_DIM + b) * OUT_DIM + cc] =
                acc[ct] + attn_b2[cc] * Sv[b * OUT_DIM + cc];
        }
    }
}

// ---------------------------------------------------------------------------
extern "C" void kernel_launch(void* const* d_in, const int* in_sizes, int n_in,
                              void* d_out, int out_size, void* d_ws, size_t ws_size,
                              hipStream_t stream)
{
    const float* x        = (const float*)d_in[0];
    const float* attn_w1  = (const float*)d_in[1];
    const float* attn_b1  = (const float*)d_in[2];
    const float* attn_w2  = (const float*)d_in[3];
    const float* attn_b2  = (const float*)d_in[4];
    const float* value_w1 = (const float*)d_in[5];
    const float* value_b1 = (const float*)d_in[6];
    const float* value_w2 = (const float*)d_in[7];
    const float* value_b2 = (const float*)d_in[8];
    float* out = (float*)d_out;

    // Workspace layout (floats): P 512K | Q 512K | V 512K | Sv 4K | W2s(bf16) 16K
    float* ws  = (float*)d_ws;
    float* P   = ws;
    float* Q   = ws + 524288;
    float* V   = ws + 1048576;
    float* Sv  = ws + 1572864;
    short* W2s = (short*)(ws + 1576960);

    k_pre<<<1088, 256, 0, stream>>>(x, attn_w1, attn_b1, attn_w2,
                                    value_w1, value_b1, value_w2, value_b2,
                                    P, Q, V, W2s);
    k_sv<<<32, 256, 0, stream>>>(V, Sv);
    k_main<<<1024, 256, 0, stream>>>(P, Q, V, Sv, W2s, attn_b2, out);
}